// Round 7
// baseline (27629.211 us; speedup 1.0000x reference)
//
#include <hip/hip_runtime.h>
#include <math.h>

#define T_STEPS 8192
#define HID 2048
#define H3 6144
#define NBLK 256
#define CHUNK 2048

typedef float f32x4 __attribute__((ext_vector_type(4)));

// ---------------------------------------------------------------------------
// Coherent (cross-XCD) access: sc0 sc1 bypasses L1/L2 to the Infinity-Cache
// coherence point. Empirically validated (R3/R4/R6) for producer/consumer h
// exchange. A single 16B dwordx4 store lands as one IC transaction.
// NOTE: inline-asm INPUTS must be ext_vector_type, not the float4 struct.
// ---------------------------------------------------------------------------
__device__ __forceinline__ float4 cload_f4(const float* p) {
    float4 r;
    asm volatile("global_load_dwordx4 %0, %1, off sc0 sc1\n\t"
                 "s_waitcnt vmcnt(0)"
                 : "=&v"(r) : "v"(p) : "memory");
    return r;
}
__device__ __forceinline__ void cstore_f4(float4* p, float x, float y,
                                          float z, float w) {
    f32x4 v; v[0] = x; v[1] = y; v[2] = z; v[3] = w;
    asm volatile("global_store_dwordx4 %0, %1, off sc0 sc1"
                 :: "v"(p), "v"(v) : "memory");
}

// ---------------------------------------------------------------------------
// fp32 GEMM: C[M,N] = A[M,K] @ B[N,K]^T + bias, optional ReLU.
// ---------------------------------------------------------------------------
template<int RELU>
__global__ __launch_bounds__(256) void sgemm_bias(
    const float* __restrict__ A, const float* __restrict__ B,
    const float* __restrict__ bias, float* __restrict__ C,
    int M, int N, int K)
{
    __shared__ float As[16][64];
    __shared__ float Bs[16][64];
    const int tid = threadIdx.x;
    const int tm = tid & 15;
    const int tn = tid >> 4;
    const int m0 = blockIdx.y * 64;
    const int n0 = blockIdx.x * 64;
    const int lm = tid >> 2;
    const int lk = (tid & 3) * 4;

    float c[4][4] = {};

    for (int k0 = 0; k0 < K; k0 += 16) {
        float4 av = *(const float4*)(A + (size_t)(m0 + lm) * K + k0 + lk);
        float4 bv = make_float4(0.f, 0.f, 0.f, 0.f);
        const int bn = n0 + lm;
        if (bn < N) bv = *(const float4*)(B + (size_t)bn * K + k0 + lk);
        __syncthreads();
        As[lk+0][lm] = av.x; As[lk+1][lm] = av.y; As[lk+2][lm] = av.z; As[lk+3][lm] = av.w;
        Bs[lk+0][lm] = bv.x; Bs[lk+1][lm] = bv.y; Bs[lk+2][lm] = bv.z; Bs[lk+3][lm] = bv.w;
        __syncthreads();
        #pragma unroll
        for (int kk = 0; kk < 16; kk++) {
            float4 a4 = *(const float4*)&As[kk][tm * 4];
            float4 b4 = *(const float4*)&Bs[kk][tn * 4];
            c[0][0] += a4.x * b4.x; c[0][1] += a4.x * b4.y; c[0][2] += a4.x * b4.z; c[0][3] += a4.x * b4.w;
            c[1][0] += a4.y * b4.x; c[1][1] += a4.y * b4.y; c[1][2] += a4.y * b4.z; c[1][3] += a4.y * b4.w;
            c[2][0] += a4.z * b4.x; c[2][1] += a4.z * b4.y; c[2][2] += a4.z * b4.z; c[2][3] += a4.z * b4.w;
            c[3][0] += a4.w * b4.x; c[3][1] += a4.w * b4.y; c[3][2] += a4.w * b4.z; c[3][3] += a4.w * b4.w;
        }
    }

    const int mrow = m0 + tm * 4;
    #pragma unroll
    for (int i = 0; i < 4; i++) {
        #pragma unroll
        for (int j = 0; j < 4; j++) {
            const int n = n0 + tn * 4 + j;
            if (n < N) {
                float v = c[i][j] + bias[n];
                if (RELU) v = fmaxf(v, 0.f);
                C[(size_t)(mrow + i) * N + n] = v;
            }
        }
    }
}

// ---------------------------------------------------------------------------
// fp32 GEMM (B not transposed): C[M,N] = A[M,K] @ B[K,N]. No bias.
// Used once: W_comb[6144,64] = w_ih[6144,2048] @ enc_w[2048,64].
// ---------------------------------------------------------------------------
__global__ __launch_bounds__(256) void sgemm_nn(
    const float* __restrict__ A, const float* __restrict__ B,
    float* __restrict__ C, int M, int N, int K)
{
    __shared__ float As[16][64];
    __shared__ float Bs[16][64];
    const int tid = threadIdx.x;
    const int tm = tid & 15;
    const int tn = tid >> 4;
    const int m0 = blockIdx.y * 64;
    const int n0 = blockIdx.x * 64;
    const int lm = tid >> 2;
    const int lk = (tid & 3) * 4;
    const int bk  = tid >> 4;
    const int bn4 = (tid & 15) * 4;

    float c[4][4] = {};

    for (int k0 = 0; k0 < K; k0 += 16) {
        float4 av = *(const float4*)(A + (size_t)(m0 + lm) * K + k0 + lk);
        float4 bv = *(const float4*)(B + (size_t)(k0 + bk) * N + n0 + bn4);
        __syncthreads();
        As[lk+0][lm] = av.x; As[lk+1][lm] = av.y; As[lk+2][lm] = av.z; As[lk+3][lm] = av.w;
        *(float4*)&Bs[bk][bn4] = bv;
        __syncthreads();
        #pragma unroll
        for (int kk = 0; kk < 16; kk++) {
            float4 a4 = *(const float4*)&As[kk][tm * 4];
            float4 b4 = *(const float4*)&Bs[kk][tn * 4];
            c[0][0] += a4.x * b4.x; c[0][1] += a4.x * b4.y; c[0][2] += a4.x * b4.z; c[0][3] += a4.x * b4.w;
            c[1][0] += a4.y * b4.x; c[1][1] += a4.y * b4.y; c[1][2] += a4.y * b4.z; c[1][3] += a4.y * b4.w;
            c[2][0] += a4.z * b4.x; c[2][1] += a4.z * b4.y; c[2][2] += a4.z * b4.z; c[2][3] += a4.z * b4.w;
            c[3][0] += a4.w * b4.x; c[3][1] += a4.w * b4.y; c[3][2] += a4.w * b4.z; c[3][3] += a4.w * b4.w;
        }
    }

    const int mrow = m0 + tm * 4;
    #pragma unroll
    for (int i = 0; i < 4; i++) {
        #pragma unroll
        for (int j = 0; j < 4; j++)
            C[(size_t)(mrow + i) * N + n0 + tn * 4 + j] = c[i][j];
    }
}

// ---------------------------------------------------------------------------
// b_comb[r] = dot(w_ih[r,:], enc_b) + b_ih[r].  One wave per row.
// ---------------------------------------------------------------------------
__global__ __launch_bounds__(256) void bcomb_kernel(
    const float* __restrict__ w_ih, const float* __restrict__ enc_b,
    const float* __restrict__ b_ih, float* __restrict__ b_comb)
{
    const int wv = threadIdx.x >> 6, lane = threadIdx.x & 63;
    const int r = blockIdx.x * 4 + wv;
    const float* row = w_ih + (size_t)r * HID;
    float acc = 0.f;
    for (int j = lane; j < HID; j += 64) acc += row[j] * enc_b[j];
    #pragma unroll
    for (int m = 32; m >= 1; m >>= 1) acc += __shfl_xor(acc, m, 64);
    if (lane == 0) b_comb[r] = acc + b_ih[r];
}

// ---------------------------------------------------------------------------
// Persistent GRU scan. 256 blocks x 1024 threads, 1 block/CU.
// Block b owns h[8b..8b+7] -> 24 rows of w_hh; wave-pair k owns rows
// idx3=3k..3k+2; thread holds 48 weight floats (12 f32x4), PINNED into
// VGPRs via opaque empty asm so the allocator cannot rematerialize the
// loads inside the loop (R6 failure: VGPR_Count=52, weights re-streamed
// through L2 every step = ~1.5us/step).
// Exchange: fused h+stamp atoms (16B, single IC transaction). Every thread
// polls ITS OWN atom; the successful poll already carries the data.
// ---------------------------------------------------------------------------
__global__ __launch_bounds__(1024, 4) void gru_scan(
    const float* __restrict__ w_hh, const float* __restrict__ b_n,
    const float* __restrict__ ig,   // [steps,3,H] fp32 for this chunk
    float* __restrict__ hs,         // [steps,H] output states (chunk base)
    float4* __restrict__ atoms,     // 2 x 1024 atoms, zeroed at launch
    int base, int steps)
{
    __shared__ float h_lds[HID];
    __shared__ float pg[16][3];
    __shared__ float hg_lds[24];
    const int tid  = threadIdx.x;
    const int lane = tid & 63;
    const int w    = tid >> 6;      // wave 0..15
    const int pr   = tid & 127;     // pair-local lane 0..127
    const int k    = tid >> 7;      // wave-pair 0..7
    const int b    = blockIdx.x;

    // ---- 48 weights per thread (12 f32x4), coalesced, then PINNED ----
    f32x4 wreg[3][4];
    #pragma unroll
    for (int j = 0; j < 3; j++) {
        const int idx3 = 3 * k + j;
        const float* wp = w_hh +
            (size_t)((idx3 >> 3) * HID + b * 8 + (idx3 & 7)) * HID;
        #pragma unroll
        for (int m = 0; m < 4; m++)
            wreg[j][m] = *(const f32x4*)(wp + 4 * pr + 512 * m);
    }
    // opaque def: values must live in VGPRs; loads can't be rematerialized
    #pragma unroll
    for (int j = 0; j < 3; j++)
        #pragma unroll
        for (int m = 0; m < 4; m++)
            asm volatile("" : "+v"(wreg[j][m]));

    const int i = b * 8 + tid;                 // valid for tid<8
    const float bn = (tid < 8) ? b_n[i] : 0.f;

    for (int t = 0; t < steps; t++) {
        // ig loads for this step (tid<8) - in flight during the poll
        float ig0 = 0.f, ig1 = 0.f, ig2 = 0.f;
        if (tid < 8) {
            const float* p = ig + (size_t)t * H3 + i;
            ig0 = p[0]; ig1 = p[HID]; ig2 = p[2 * HID];
        }

        // ---- poll own atom: one IC round trip returns stamp AND data ----
        const float target = (float)(base + t);          // exact in fp32
        const float* ap = (const float*)(atoms + (t & 1) * 1024 + tid);
        float4 f;
        do { f = cload_f4(ap); } while (f.z < target);
        *(float2*)&h_lds[2 * tid] = make_float2(f.x, f.y);
        __syncthreads();

        // ---- dot: rows 3k..3k+2, cols 4*pr+512m, weights in registers ----
        f32x4 v0 = 0.f, v1 = 0.f, v2 = 0.f;
        #pragma unroll
        for (int m = 0; m < 4; m++) {
            f32x4 h4 = *(const f32x4*)&h_lds[4 * pr + 512 * m];
            v0 += wreg[0][m] * h4;
            v1 += wreg[1][m] * h4;
            v2 += wreg[2][m] * h4;
        }
        float a0 = (v0[0] + v0[1]) + (v0[2] + v0[3]);
        float a1 = (v1[0] + v1[1]) + (v1[2] + v1[3]);
        float a2 = (v2[0] + v2[1]) + (v2[2] + v2[3]);
        #pragma unroll
        for (int s = 32; s >= 1; s >>= 1) {
            a0 += __shfl_xor(a0, s, 64);
            a1 += __shfl_xor(a1, s, 64);
            a2 += __shfl_xor(a2, s, 64);
        }
        if (lane == 0) { pg[w][0] = a0; pg[w][1] = a1; pg[w][2] = a2; }
        __syncthreads();

        // ---- combine + gates + publish (all in wave 0, lockstep) ----
        if (w == 0) {
            if (lane < 24) {
                const int kk = lane / 3, j = lane - 3 * kk;
                hg_lds[lane] = pg[2 * kk][j] + pg[2 * kk + 1][j];
            }
            asm volatile("s_waitcnt lgkmcnt(0)" ::: "memory");  // intra-wave LDS wr->rd
            float h_new = 0.f;
            if (lane < 8) {
                const float r = 1.f / (1.f + expf(-(ig0 + hg_lds[lane])));
                const float z = 1.f / (1.f + expf(-(ig1 + hg_lds[8 + lane])));
                const float n = tanhf(ig2 + r * (hg_lds[16 + lane] + bn));
                const float hp = h_lds[i];
                h_new = n + z * (hp - n);
                hs[(size_t)t * HID + i] = h_new;     // plain cached store
            }
            const float ha = __shfl(h_new, lane * 2, 64);
            const float hb = __shfl(h_new, lane * 2 + 1, 64);
            if (lane < 4) {
                cstore_f4(atoms + ((t + 1) & 1) * 1024 + b * 4 + lane,
                          ha, hb, (float)(base + t + 1), 0.f);
            }
        }
        // no end barrier: self-atom gating + top barrier provide ordering
    }
}

// ---------------------------------------------------------------------------
extern "C" void kernel_launch(void* const* d_in, const int* in_sizes, int n_in,
                              void* d_out, int out_size, void* d_ws, size_t ws_size,
                              hipStream_t stream) {
    const float* x     = (const float*)d_in[0];
    const float* enc_w = (const float*)d_in[1];
    const float* enc_b = (const float*)d_in[2];
    const float* w_ih  = (const float*)d_in[3];
    const float* w_hh  = (const float*)d_in[4];
    const float* b_ih  = (const float*)d_in[5];
    const float* b_n   = (const float*)d_in[6];
    const float* w0    = (const float*)d_in[7];
    const float* b0    = (const float*)d_in[8];
    const float* w1    = (const float*)d_in[9];
    const float* b1    = (const float*)d_in[10];
    const float* w2    = (const float*)d_in[11];
    const float* b2    = (const float*)d_in[12];
    float* out = (float*)d_out;

    // workspace (~136 MB): R1 64MB (ig chunk -> dec h1), R2 64MB (hs -> dec h2)
    float* R1    = (float*)d_ws;                          // 16,777,216 f
    float* R2    = R1 + (size_t)16777216;                 // 16,777,216 f
    float* wcomb = R2 + (size_t)16777216;                 // 393,216 f
    float* bcomb = wcomb + 393216;                        // 6,144 f
    float4* atoms = (float4*)(bcomb + 6144);              // 2*1024 float4 = 32KB

    (void)hipMemsetAsync(atoms, 0, 2 * 1024 * sizeof(float4), stream);

    // fold encoder into GRU input weights:
    //   W_comb = w_ih @ enc_w   [6144,64];  b_comb = w_ih @ enc_b + b_ih
    sgemm_nn<<<dim3(1, 96), 256, 0, stream>>>(w_ih, enc_w, wcomb, 6144, 64, 2048);
    bcomb_kernel<<<dim3(1536), 256, 0, stream>>>(w_ih, enc_b, b_ih, bcomb);

    // chunked: ig = x @ W_comb^T + b_comb (K=64), then sequential scan
    for (int c = 0; c < T_STEPS / CHUNK; c++) {
        sgemm_bias<0><<<dim3(H3 / 64, CHUNK / 64), 256, 0, stream>>>(
            x + (size_t)c * CHUNK * 64, wcomb, bcomb, R1, CHUNK, H3, 64);
        gru_scan<<<dim3(NBLK), dim3(1024), 0, stream>>>(
            w_hh, b_n, R1, R2 + (size_t)c * CHUNK * HID, atoms, c * CHUNK, CHUNK);
    }

    // decoder MLP (aliased: R2=hs -> R1=h1 -> R2=h2 -> out)
    sgemm_bias<1><<<dim3(HID / 64, T_STEPS / 64), 256, 0, stream>>>(
        R2, w0, b0, R1, T_STEPS, HID, HID);
    sgemm_bias<1><<<dim3(HID / 64, T_STEPS / 64), 256, 0, stream>>>(
        R1, w1, b1, R2, T_STEPS, HID, HID);
    sgemm_bias<0><<<dim3(1, T_STEPS / 64), 256, 0, stream>>>(
        R2, w2, b2, out, T_STEPS, 49, 2048);
}